// Round 6
// baseline (1008.140 us; speedup 1.0000x reference)
//
#include <hip/hip_runtime.h>
#include <cstdint>
#include <cstddef>

#define NN 100000
#define NP 100096          // rows padded to multiple of 64
#define EE 1600000
#define ET 1700000         // EE + NN self-loops
#define NBKT 196           // ceil(NN/512) dst-range buckets
#define TILE 2048          // edges per k_bucket block
#define STATB 256          // colsum partial blocks
#define SLICE_STRIDE ((size_t)NP * 16)   // shorts per 16-col slice

typedef short  bf16x8 __attribute__((ext_vector_type(8)));
typedef float  f32x4  __attribute__((ext_vector_type(4)));

__device__ __forceinline__ float leaky(float v) { return v > 0.f ? v : 0.2f * v; }

__device__ __forceinline__ unsigned short f2bf(float f) {
    unsigned int x = __builtin_bit_cast(unsigned int, f);
    x += 0x7FFFu + ((x >> 16) & 1u);   // RNE
    return (unsigned short)(x >> 16);
}
__device__ __forceinline__ unsigned int pk2(float lo, float hi) {
    return ((unsigned int)f2bf(hi) << 16) | (unsigned int)f2bf(lo);
}
__device__ __forceinline__ float bflo(unsigned int u) {
    return __builtin_bit_cast(float, u << 16);
}
__device__ __forceinline__ float bfhi(unsigned int u) {
    return __builtin_bit_cast(float, u & 0xFFFF0000u);
}

// ======================= CSR build via 2-level bucket sort =======================
__global__ void k_bcount(const int* __restrict__ ei, int* __restrict__ btot) {
    __shared__ int h[256];
    int t = threadIdx.x;
    h[t] = 0;
    __syncthreads();
    for (int e = blockIdx.x * 256 + t; e < ET; e += 256 * 256) {
        int d = (e < EE) ? ei[EE + e] : (e - EE);
        atomicAdd(&h[d >> 9], 1);
    }
    __syncthreads();
    if (h[t]) atomicAdd(&btot[t], h[t]);
}

__global__ void k_bscan(const int* __restrict__ btot, int* __restrict__ bstart,
                        int* __restrict__ bcur, int* __restrict__ off) {
    __shared__ int s[256];
    int t = threadIdx.x;
    int v = (t < NBKT) ? btot[t] : 0;
    s[t] = v;
    __syncthreads();
    for (int o = 1; o < 256; o <<= 1) {
        int a = (t >= o) ? s[t - o] : 0;
        __syncthreads();
        s[t] += a;
        __syncthreads();
    }
    int ex = s[t] - v;
    if (t <= NBKT) bstart[t] = (t < NBKT) ? ex : ET;
    if (t == NBKT - 1) bstart[NBKT] = s[t];
    bcur[t] = ex;
    if (t == 0) off[NN] = ET;
}

__global__ __launch_bounds__(256) void k_bucket(
    const int* __restrict__ ei, int* __restrict__ bcur, unsigned int* __restrict__ bucketed)
{
    __shared__ int h4[4][256], woff[4][256], loff[256], gbase[256], sc[256];
    __shared__ unsigned int stage[TILE];
    __shared__ int gaddr[TILE];
    __shared__ int stot_s;
    const int t = threadIdx.x;
    const int w = t >> 6;
    const int e0 = blockIdx.x * TILE;

    h4[0][t] = 0; h4[1][t] = 0; h4[2][t] = 0; h4[3][t] = 0;
    __syncthreads();

    unsigned int pk[TILE / 256];
    int bk[TILE / 256];
#pragma unroll
    for (int i = 0; i < TILE / 256; ++i) {
        int e = e0 + i * 256 + t;
        bk[i] = -1;
        if (e < ET) {
            int s, d;
            if (e < EE) { s = ei[e]; d = ei[EE + e]; } else { s = e - EE; d = s; }
            bk[i] = d >> 9;
            pk[i] = ((unsigned int)(d & 511) << 17) | (unsigned int)s;
            atomicAdd(&h4[w][bk[i]], 1);
        }
    }
    __syncthreads();

    int h0 = h4[0][t], h1 = h4[1][t], h2 = h4[2][t], h3 = h4[3][t];
    int tot = h0 + h1 + h2 + h3;
    sc[t] = tot;
    __syncthreads();
    for (int o = 1; o < 256; o <<= 1) {
        int a = (t >= o) ? sc[t - o] : 0;
        __syncthreads();
        sc[t] += a;
        __syncthreads();
    }
    int lo = sc[t] - tot;
    loff[t] = lo;
    woff[0][t] = lo;
    woff[1][t] = lo + h0;
    woff[2][t] = lo + h0 + h1;
    woff[3][t] = lo + h0 + h1 + h2;
    if (t < NBKT && tot) gbase[t] = atomicAdd(&bcur[t], tot);
    if (t == 255) stot_s = sc[255];
    h4[0][t] = 0; h4[1][t] = 0; h4[2][t] = 0; h4[3][t] = 0;
    __syncthreads();

#pragma unroll
    for (int i = 0; i < TILE / 256; ++i) {
        if (bk[i] >= 0) {
            int b = bk[i];
            int r = woff[w][b] + atomicAdd(&h4[w][b], 1);
            stage[r] = pk[i];
            gaddr[r] = gbase[b] + (r - loff[b]);
        }
    }
    __syncthreads();

    const int stot = stot_s;
    for (int j = t; j < stot; j += 256)
        bucketed[gaddr[j]] = stage[j];
}

__global__ __launch_bounds__(256) void k_csr(
    const unsigned int* __restrict__ bucketed, const int* __restrict__ bstart,
    int* __restrict__ off, int* __restrict__ srcs)
{
    __shared__ int h[512], sc2[512], c2[512], sp[256];
    const int t = threadIdx.x;
    const int b = blockIdx.x;
    const int beg = bstart[b], end = bstart[b + 1];
    const int cnt = end - beg;

    h[t] = 0; h[t + 256] = 0; c2[t] = 0; c2[t + 256] = 0;
    __syncthreads();
    for (int i = t; i < cnt; i += 256)
        atomicAdd(&h[bucketed[beg + i] >> 17], 1);
    __syncthreads();

    int a0 = h[2 * t], a1 = h[2 * t + 1];
    sp[t] = a0 + a1;
    __syncthreads();
    for (int o = 1; o < 256; o <<= 1) {
        int a = (t >= o) ? sp[t - o] : 0;
        __syncthreads();
        sp[t] += a;
        __syncthreads();
    }
    int ep = sp[t] - (a0 + a1);
    sc2[2 * t] = ep;
    sc2[2 * t + 1] = ep + a0;
    __syncthreads();

    const int d0 = b << 9;
#pragma unroll
    for (int k = t; k < 512; k += 256) {
        int d = d0 + k;
        if (d < NN) off[d] = beg + sc2[k];
    }

    for (int i = t; i < cnt; i += 256) {
        unsigned int v = bucketed[beg + i];
        int ld = v >> 17;
        int r = atomicAdd(&c2[ld], 1);
        srcs[beg + sc2[ld] + r] = (int)(v & 0x1FFFFu);
    }
}

// ======================= weight conversion (all 3 at once) =======================
__global__ void k_cvtw3(const float* __restrict__ W0, const float* __restrict__ W1,
                        const float* __restrict__ W2, unsigned short* __restrict__ B0,
                        unsigned short* __restrict__ B1, unsigned short* __restrict__ B2)
{
    int i = blockIdx.x * 256 + threadIdx.x;   // 3*16384
    int w = i >> 14, j = i & 16383;
    const float* src = (w == 0) ? W0 : (w == 1) ? W1 : W2;
    unsigned short* dst = (w == 0) ? B0 : (w == 1) ? B1 : B2;
    dst[j] = f2bf(src[j]);
}

// ======================= MFMA GEMM: H = X @ W^T, sliced-H out, fused AS/AD ==========
// MODE 0: fp32 input (layer 0); MODE 1: bf16 input + BN affine + relu
template<int MODE>
__global__ __launch_bounds__(256) void k_mfma(
    const float* __restrict__ Xf, const unsigned short* __restrict__ X16,
    const unsigned short* __restrict__ Wb,
    const float* __restrict__ scale, const float* __restrict__ shift,
    const float* __restrict__ asrc, const float* __restrict__ adst,
    unsigned short* __restrict__ Hs, float* __restrict__ AS, float* __restrict__ AD)
{
    __shared__ float hst[4][16][132];
    const int t    = threadIdx.x;
    const int w    = t >> 6;
    const int lane = t & 63;
    const int c    = lane & 15;
    const int q    = lane >> 4;
    const int r0   = blockIdx.x * 64 + w * 16;
    const int row  = r0 + c;

    union { uint4 u; bf16x8 v; } Af[4];
    if (row < NN) {
#pragma unroll
        for (int k0 = 0; k0 < 4; ++k0) {
            float a0,a1,a2,a3,b0,b1,b2,b3;
            if (MODE == 0) {
                const float* xp = Xf + ((size_t)row << 7) + (q << 3);
                float4 a = *(const float4*)(xp + (k0 << 5));
                float4 b = *(const float4*)(xp + (k0 << 5) + 4);
                a0=a.x;a1=a.y;a2=a.z;a3=a.w;b0=b.x;b1=b.y;b2=b.z;b3=b.w;
            } else {
                const unsigned short* xp = X16 + ((size_t)row << 7) + (q << 3);
                uint4 u = *(const uint4*)(xp + (k0 << 5));
                a0=bflo(u.x);a1=bfhi(u.x);a2=bflo(u.y);a3=bfhi(u.y);
                b0=bflo(u.z);b1=bfhi(u.z);b2=bflo(u.w);b3=bfhi(u.w);
                const int kb = (k0 << 5) + (q << 3);
                float4 sA = *(const float4*)&scale[kb];
                float4 sB = *(const float4*)&scale[kb + 4];
                float4 hA = *(const float4*)&shift[kb];
                float4 hB = *(const float4*)&shift[kb + 4];
                a0 = fmaxf(0.f, fmaf(a0, sA.x, hA.x));
                a1 = fmaxf(0.f, fmaf(a1, sA.y, hA.y));
                a2 = fmaxf(0.f, fmaf(a2, sA.z, hA.z));
                a3 = fmaxf(0.f, fmaf(a3, sA.w, hA.w));
                b0 = fmaxf(0.f, fmaf(b0, sB.x, hB.x));
                b1 = fmaxf(0.f, fmaf(b1, sB.y, hB.y));
                b2 = fmaxf(0.f, fmaf(b2, sB.z, hB.z));
                b3 = fmaxf(0.f, fmaf(b3, sB.w, hB.w));
            }
            Af[k0].u.x = pk2(a0, a1);
            Af[k0].u.y = pk2(a2, a3);
            Af[k0].u.z = pk2(b0, b1);
            Af[k0].u.w = pk2(b2, b3);
        }
    } else {
#pragma unroll
        for (int k0 = 0; k0 < 4; ++k0) Af[k0].u = make_uint4(0, 0, 0, 0);
    }

    f32x4 acc[8];
#pragma unroll
    for (int nt = 0; nt < 8; ++nt) acc[nt] = (f32x4){0.f, 0.f, 0.f, 0.f};

#pragma unroll
    for (int nt = 0; nt < 8; ++nt) {
        union { uint4 u; bf16x8 v; } Bf[4];
        const size_t bbase = ((size_t)(nt * 16 + c) << 7) + (q << 3);
#pragma unroll
        for (int k0 = 0; k0 < 4; ++k0)
            Bf[k0].u = *(const uint4*)(Wb + bbase + (k0 << 5));
#pragma unroll
        for (int k0 = 0; k0 < 4; ++k0)
            acc[nt] = __builtin_amdgcn_mfma_f32_16x16x32_bf16(Af[k0].v, Bf[k0].v, acc[nt], 0, 0, 0);
    }

    // fused AS/AD; C/D layout col=lane&15, row=q*4+reg
    float ps[4] = {0.f, 0.f, 0.f, 0.f}, pd[4] = {0.f, 0.f, 0.f, 0.f};
#pragma unroll
    for (int nt = 0; nt < 8; ++nt) {
        float av = asrc[nt * 16 + c];
        float dv = adst[nt * 16 + c];
#pragma unroll
        for (int r = 0; r < 4; ++r) {
            ps[r] = fmaf(acc[nt][r], av, ps[r]);
            pd[r] = fmaf(acc[nt][r], dv, pd[r]);
        }
    }
#pragma unroll
    for (int m = 1; m < 16; m <<= 1) {
#pragma unroll
        for (int r = 0; r < 4; ++r) { ps[r] += __shfl_xor(ps[r], m); pd[r] += __shfl_xor(pd[r], m); }
    }
    if (c == 0) {
#pragma unroll
        for (int r = 0; r < 4; ++r) {
            int grow = r0 + q * 4 + r;
            if (grow < NN) { AS[grow] = ps[r]; AD[grow] = pd[r]; }
        }
    }

    // H store: LDS transpose, then 16-col slice-major bf16 writes
#pragma unroll
    for (int nt = 0; nt < 8; ++nt)
#pragma unroll
        for (int r = 0; r < 4; ++r)
            hst[w][q * 4 + r][nt * 16 + c] = acc[nt][r];
    __syncthreads();
    {
        const int orow = lane >> 2, seg = lane & 3;
        const int grow = r0 + orow;
        if (grow < NN) {
#pragma unroll
            for (int hs = 0; hs < 2; ++hs) {
                const int sl = seg * 2 + hs;
                float4 a = *(const float4*)&hst[w][orow][sl * 16];
                float4 b = *(const float4*)&hst[w][orow][sl * 16 + 4];
                float4 cc = *(const float4*)&hst[w][orow][sl * 16 + 8];
                float4 d = *(const float4*)&hst[w][orow][sl * 16 + 12];
                uint4 o1, o2;
                o1.x = pk2(a.x, a.y);  o1.y = pk2(a.z, a.w);
                o1.z = pk2(b.x, b.y);  o1.w = pk2(b.z, b.w);
                o2.x = pk2(cc.x, cc.y); o2.y = pk2(cc.z, cc.w);
                o2.z = pk2(d.x, d.y);  o2.w = pk2(d.z, d.w);
                unsigned short* dp = Hs + (size_t)sl * SLICE_STRIDE + ((size_t)grow << 4);
                *(uint4*)dp = o1;
                *(uint4*)(dp + 8) = o2;
            }
        }
    }
}

// ======================= per-node normalized edge weights =======================
// ealpha[e] = (src, alpha) with alpha = exp(leaky(AS[src]+AD[dst])) / den(dst)
__global__ __launch_bounds__(256) void k_alpha(
    const int* __restrict__ off, const int* __restrict__ srcs,
    const float* __restrict__ AS, const float* __restrict__ AD,
    uint2* __restrict__ ealpha)
{
    const int wid  = threadIdx.x >> 6;
    const int lane = threadIdx.x & 63;
    const int n    = blockIdx.x * 4 + wid;
    const int beg = off[n], end = off[n + 1];
    const float adn = AD[n];

    float den = 0.f;
    for (int i = beg + lane; i < end; i += 64) {
        int s = srcs[i];
        float e = AS[s] + adn;
        e = (e > 0.f) ? e : 0.2f * e;
        float wgt = __expf(e);
        ealpha[i] = make_uint2((unsigned int)s, __builtin_bit_cast(unsigned int, wgt));
        den += wgt;
    }
#pragma unroll
    for (int o = 32; o; o >>= 1) den += __shfl_xor(den, o);
    float inv = 1.f / den;
    for (int i = beg + lane; i < end; i += 64) {
        float* ap = (float*)&ealpha[i].y;
        *ap = *ap * inv;
    }
}

// ======================= sliced gather: OUT[:, s*16:(s+1)*16] = sum alpha*h ==========
// slice = blockIdx.x & 7  -> round-robin block->XCD mapping pins each 3.2MB slice
// to one XCD's L2. 16 nodes/block (4 waves x 4 nodes); 16 edges/iter x 4 col-lanes.
template<int FINAL>
__global__ __launch_bounds__(256) void k_gather(
    const int* __restrict__ off, const uint2* __restrict__ ealpha,
    const unsigned short* __restrict__ Hs, const float* __restrict__ bias,
    unsigned short* __restrict__ OUTb, float* __restrict__ OUTf)
{
    const int s    = blockIdx.x & 7;
    const int nb   = blockIdx.x >> 3;
    const int wid  = threadIdx.x >> 6;
    const int lane = threadIdx.x & 63;
    const int g    = lane >> 2;     // edge subgroup 0..15
    const int c4   = lane & 3;      // 4-col group
    const unsigned short* Hsl = Hs + (size_t)s * SLICE_STRIDE;
    float4 bv = *(const float4*)&bias[s * 16 + c4 * 4];

#pragma unroll
    for (int r = 0; r < 4; ++r) {
        const int n = nb * 16 + wid * 4 + r;
        const int beg = off[n], end = off[n + 1];
        float4 acc = make_float4(0.f, 0.f, 0.f, 0.f);
        for (int base = beg; base < end; base += 16) {
            int i = base + g;
            uint2 ea = (i < end) ? ealpha[i] : make_uint2(0u, 0u);
            float al = __builtin_bit_cast(float, ea.y);
            uint2 u = *(const uint2*)(Hsl + ((size_t)ea.x << 4) + (c4 << 2));
            acc.x = fmaf(al, bflo(u.x), acc.x);
            acc.y = fmaf(al, bfhi(u.x), acc.y);
            acc.z = fmaf(al, bflo(u.y), acc.z);
            acc.w = fmaf(al, bfhi(u.y), acc.w);
        }
#pragma unroll
        for (int o = 4; o < 64; o <<= 1) {
            acc.x += __shfl_xor(acc.x, o);
            acc.y += __shfl_xor(acc.y, o);
            acc.z += __shfl_xor(acc.z, o);
            acc.w += __shfl_xor(acc.w, o);
        }
        if (g == 0) {
            float4 o4 = make_float4(acc.x + bv.x, acc.y + bv.y, acc.z + bv.z, acc.w + bv.w);
            if (FINAL) {
                *(float4*)(OUTf + ((size_t)n << 7) + s * 16 + c4 * 4) = o4;
            } else {
                ushort4 p;
                p.x = f2bf(o4.x); p.y = f2bf(o4.y); p.z = f2bf(o4.z); p.w = f2bf(o4.w);
                *(ushort4*)(OUTb + ((size_t)n << 7) + s * 16 + c4 * 4) = p;
            }
        }
    }
}

// ======================= batchnorm stats (bf16 input, partials) =======================
__global__ __launch_bounds__(256) void k_colsum(const unsigned short* __restrict__ Ob,
                                                float* __restrict__ part_s, float* __restrict__ part_q)
{
    __shared__ float l0[256], l1[256];
    const unsigned int* O32 = (const unsigned int*)Ob;
    const int t = threadIdx.x;
    const int cp = t & 63;      // column pair
    const int qt = t >> 6;      // row group 0..3
    float sl = 0.f, sh = 0.f, ql = 0.f, qh = 0.f;
    for (int r = blockIdx.x * 4 + qt; r < NN; r += STATB * 4) {
        unsigned int u = O32[(size_t)r * 64 + cp];
        float lo = bflo(u), hi = bfhi(u);
        sl += lo; sh += hi; ql += lo * lo; qh += hi * hi;
    }
    l0[t] = sl; l1[t] = sh;
    __syncthreads();
    if (t < 64) {
        float a = l0[t] + l0[64 + t] + l0[128 + t] + l0[192 + t];
        float b = l1[t] + l1[64 + t] + l1[128 + t] + l1[192 + t];
        part_s[blockIdx.x * 128 + 2 * t]     = a;
        part_s[blockIdx.x * 128 + 2 * t + 1] = b;
    }
    __syncthreads();
    l0[t] = ql; l1[t] = qh;
    __syncthreads();
    if (t < 64) {
        float a = l0[t] + l0[64 + t] + l0[128 + t] + l0[192 + t];
        float b = l1[t] + l1[64 + t] + l1[128 + t] + l1[192 + t];
        part_q[blockIdx.x * 128 + 2 * t]     = a;
        part_q[blockIdx.x * 128 + 2 * t + 1] = b;
    }
}

__global__ void k_bnfinal(const float* __restrict__ part_s, const float* __restrict__ part_q,
                          const float* __restrict__ gamma, const float* __restrict__ beta,
                          float* __restrict__ scale, float* __restrict__ shift) {
    int c = threadIdx.x;
    float s = 0.f, q = 0.f;
    for (int b = 0; b < STATB; ++b) { s += part_s[b * 128 + c]; q += part_q[b * 128 + c]; }
    float mu  = s * (1.f / NN);
    float var = q * (1.f / NN) - mu * mu;
    float sc  = gamma[c] * rsqrtf(var + 1e-5f);
    scale[c] = sc;
    shift[c] = beta[c] - mu * sc;
}

extern "C" void kernel_launch(void* const* d_in, const int* in_sizes, int n_in,
                              void* d_out, int out_size, void* d_ws, size_t ws_size,
                              hipStream_t stream)
{
    const float* x  = (const float*)d_in[0];
    const int*   ei = (const int*)d_in[1];
    const float* Wm[3]  = {(const float*)d_in[2], (const float*)d_in[6],  (const float*)d_in[10]};
    const float* Asr[3] = {(const float*)d_in[3], (const float*)d_in[7],  (const float*)d_in[11]};
    const float* Ads[3] = {(const float*)d_in[4], (const float*)d_in[8],  (const float*)d_in[12]};
    const float* Bs[3]  = {(const float*)d_in[5], (const float*)d_in[9],  (const float*)d_in[13]};
    const float* gam[2] = {(const float*)d_in[14], (const float*)d_in[16]};
    const float* bet[2] = {(const float*)d_in[15], (const float*)d_in[17]};

    char* p = (char*)d_ws;
    auto carve = [&](size_t bytes) -> char* {
        char* r = p;
        p += (bytes + 255) & ~(size_t)255;
        return r;
    };
    int*   off_   = (int*)carve((size_t)(NN + 1) * 4);
    int*   srcs   = (int*)carve((size_t)ET * 4);
    unsigned int* bucketed = (unsigned int*)carve((size_t)ET * 4);
    uint2* ealpha = (uint2*)carve((size_t)ET * 8);
    int*   btot   = (int*)carve(256 * 4);
    int*   bstart = (int*)carve(260 * 4);
    int*   bcur   = (int*)carve(256 * 4);
    unsigned short* Hs   = (unsigned short*)carve((size_t)NP * 128 * 2);  // slice-major
    unsigned short* OUTb = (unsigned short*)carve((size_t)NP * 128 * 2);  // bf16 intermediate
    unsigned short* Wb[3];
    Wb[0] = (unsigned short*)carve(16384 * 2);
    Wb[1] = (unsigned short*)carve(16384 * 2);
    Wb[2] = (unsigned short*)carve(16384 * 2);
    float* AS     = (float*)carve((size_t)NN * 4);
    float* AD     = (float*)carve((size_t)NN * 4);
    float* part_s = (float*)carve((size_t)STATB * 128 * 4);
    float* part_q = (float*)carve((size_t)STATB * 128 * 4);
    float* scale  = (float*)carve(128 * 4);
    float* shift  = (float*)carve(128 * 4);

    float* OUTf = (float*)d_out;

    // CSR build (bucket sort)
    (void)hipMemsetAsync(btot, 0, 256 * 4, stream);
    k_bcount<<<256, 256, 0, stream>>>(ei, btot);
    k_bscan<<<1, 256, 0, stream>>>(btot, bstart, bcur, off_);
    k_bucket<<<(ET + TILE - 1) / TILE, 256, 0, stream>>>(ei, bcur, bucketed);
    k_csr<<<NBKT, 256, 0, stream>>>(bucketed, bstart, off_, srcs);

    k_cvtw3<<<192, 256, 0, stream>>>(Wm[0], Wm[1], Wm[2], Wb[0], Wb[1], Wb[2]);

    const int MFMA_GRID = NP / 64;
    const int GATH_GRID = 8 * (NN / 16);
    const int ALPH_GRID = NN / 4;

    // layer 0
    k_mfma<0><<<MFMA_GRID, 256, 0, stream>>>(x, nullptr, Wb[0], nullptr, nullptr,
                                             Asr[0], Ads[0], Hs, AS, AD);
    k_alpha<<<ALPH_GRID, 256, 0, stream>>>(off_, srcs, AS, AD, ealpha);
    k_gather<0><<<GATH_GRID, 256, 0, stream>>>(off_, ealpha, Hs, Bs[0], OUTb, nullptr);
    k_colsum<<<STATB, 256, 0, stream>>>(OUTb, part_s, part_q);
    k_bnfinal<<<1, 128, 0, stream>>>(part_s, part_q, gam[0], bet[0], scale, shift);

    // layer 1
    k_mfma<1><<<MFMA_GRID, 256, 0, stream>>>(nullptr, OUTb, Wb[1], scale, shift,
                                             Asr[1], Ads[1], Hs, AS, AD);
    k_alpha<<<ALPH_GRID, 256, 0, stream>>>(off_, srcs, AS, AD, ealpha);
    k_gather<0><<<GATH_GRID, 256, 0, stream>>>(off_, ealpha, Hs, Bs[1], OUTb, nullptr);
    k_colsum<<<STATB, 256, 0, stream>>>(OUTb, part_s, part_q);
    k_bnfinal<<<1, 128, 0, stream>>>(part_s, part_q, gam[1], bet[1], scale, shift);

    // layer 2 (final fp32 output)
    k_mfma<1><<<MFMA_GRID, 256, 0, stream>>>(nullptr, OUTb, Wb[2], scale, shift,
                                             Asr[2], Ads[2], Hs, AS, AD);
    k_alpha<<<ALPH_GRID, 256, 0, stream>>>(off_, srcs, AS, AD, ealpha);
    k_gather<1><<<GATH_GRID, 256, 0, stream>>>(off_, ealpha, Hs, Bs[2], nullptr, OUTf);
}